// Round 11
// baseline (105.006 us; speedup 1.0000x reference)
//
#include <hip/hip_runtime.h>
#include <hip/hip_bf16.h>
#include <cstddef>
#include <cstdint>

// Direct-conv reformulation of the Winograd reference (validated r1-r10):
// out[b,o,2i+p,2j+q] = bias[o] + sum_{c,y,x} xpad[b,c,2i-1+y,2j-1+x] * Keff[o,c,p,q,y,x]
// Implicit GEMM: M=65536, N=384, K=1024, bf16 MFMA. Round 11:
//  PRE-PASS: x (fp32) -> padded bf16 image I[b][c][py 0..129][68 dw] (36 MB, d_ws);
//  pads (1 col left, 7 right, 1 row top/bottom) baked in as zeros.
//  Main loop becomes pure-DMA m97 skeleton: per chunk {vmcnt(0)+barrier; 6x
//  global_load_lds (4 A + 2 X, X is a per-lane gather from the image); 32 MFMA}.
//  No reg-staging, no cvt, no ds_write, no masks in the hot loop (~72 instr/chunk
//  vs r9's ~170). X LDS rows interleaved [kk][y*2+cs] pitch 68 dw -> l4 bank
//  windows {0,16,4,20}: 2-bank overlap only. A path verbatim r8.
//  ws_size gate: falls back to the r9 kernel (keff only) if scratch < 36 MB.

#define IHW 128
#define CIN 64
#define COUT 96
#define NCK 16

typedef __attribute__((ext_vector_type(8))) short short8_t;
typedef __attribute__((ext_vector_type(4))) float floatx4;

__device__ __forceinline__ short bf16r(float f) {
  uint32_t u = __float_as_uint(f);
  uint32_t r = (u + 0x7FFFu + ((u >> 16) & 1u)) >> 16;
  return (short)r;
}

__device__ __forceinline__ uint32_t pk(float lo, float hi) {
  union { __hip_bfloat16 h; unsigned short s; } a, bq;
  a.h = __float2bfloat16(lo);
  bq.h = __float2bfloat16(hi);
  return (uint32_t)a.s | ((uint32_t)bq.s << 16);
}

// ---------------- Keff precompute ----------------
__global__ void keff_kernel(const float* __restrict__ w, short* __restrict__ keff) {
  int idx = blockIdx.x * 256 + threadIdx.x;
  if (idx >= COUT * CIN) return;
  int o = idx / CIN, c = idx % CIN;
  int g = o / 32;

  int perm[4] = {0, 1, 2, 3};
  if (g == 1) { perm[0] = 1; perm[1] = 0; }
  else if (g == 2) { perm[0] = 3; perm[3] = 0; }

  const float H[4][4] = {{1,1,1,1},{1,-1,1,-1},{1,1,-1,-1},{1,-1,-1,1}};
  float S[2][4];
#pragma unroll
  for (int p = 0; p < 2; ++p)
#pragma unroll
    for (int a = 0; a < 4; ++a) {
      bool pos = (g == 1) ? ((p == 0) ? true : (a < 2))
                          : ((p == 0) ? ((a & 1) == 0) : (a < 2));
      S[p][a] = pos ? 1.f : -1.f;
    }

  float wv[4][4];
#pragma unroll
  for (int a = 0; a < 4; ++a)
#pragma unroll
    for (int d = 0; d < 4; ++d) wv[a][d] = w[(o * CIN + c) * 16 + a * 4 + d];

  for (int p = 0; p < 2; ++p)
    for (int q = 0; q < 2; ++q) {
      int n = o * 4 + p * 2 + q;
      for (int y = 0; y < 4; ++y)
        for (int xx = 0; xx < 4; ++xx) {
          float s = 0.f;
#pragma unroll
          for (int a = 0; a < 4; ++a) {
            float ea = S[p][a] * H[a][perm[xx]];
#pragma unroll
            for (int d = 0; d < 4; ++d) s += ea * S[q][d] * H[d][perm[y]] * wv[a][d];
          }
          keff[n * 1024 + c * 16 + y * 4 + xx] = bf16r(s);
        }
    }
}

// ---------------- pre-pass: fp32 x -> padded bf16 image ----------------
// I[(b*64+c)*130 + py][68 dw]; padded col pc = 2d+h: pc=0 pad, 1..128 = gx 0..127,
// 129..135 pad; rows py=0,129 all-zero. One thread per 16B output unit.
__global__ __launch_bounds__(256) void prepass(const float* __restrict__ x,
                                               uint32_t* __restrict__ img) {
  const int u = blockIdx.x * 256 + threadIdx.x;   // 0 .. 2,263,039
  const int u17 = u % 17;
  const int r = u / 17;                           // 0 .. 133,119
  const int py = r % 130;
  const int rc = r / 130;                         // b*64 + c
  uint32_t d0 = 0, d1 = 0, d2 = 0, d3 = 0;
  if (py != 0 && py != 129) {
    const float* xrow = x + ((size_t)rc * IHW + (py - 1)) * IHW;
    const int pc0 = u17 * 8;
    float v[8];
#pragma unroll
    for (int e = 0; e < 8; ++e) {
      const int gx = pc0 + e - 1;
      v[e] = ((unsigned)gx < (unsigned)IHW) ? xrow[gx] : 0.f;
    }
    d0 = pk(v[0], v[1]); d1 = pk(v[2], v[3]);
    d2 = pk(v[4], v[5]); d3 = pk(v[6], v[7]);
  }
  uint4* dst = reinterpret_cast<uint4*>(img + (size_t)r * 68 + u17 * 4);
  *dst = make_uint4(d0, d1, d2, d3);
}

// ---------------- main conv kernel (pre-pass path) ----------------
// block: 256 threads = 4 waves (2 M x 2 N). Tile M=128 (i-pair x 64 j), N=128.
// grid 1536, XCD-paired. LDS: A dbuf 2x16K + X dbuf 2x6528B (408 units).
#define XBUF_DW 1632   // 408 units * 4 dw
#define ABUF_DW 4096

__global__ __launch_bounds__(256) void conv_mfma(const uint32_t* __restrict__ img,
                                                 const short* __restrict__ keff,
                                                 const float* __restrict__ bias,
                                                 float* __restrict__ out) {
  __shared__ uint32_t xlds[2 * XBUF_DW];  // 13,056 B
  __shared__ uint32_t alds[2 * ABUF_DW];  // 32,768 B

  const int tid = threadIdx.x;
  const int lane = tid & 63;
  const int wid = tid >> 6;
  const int wavem = wid >> 1;
  const int wn = wid & 1;
  const int l15 = lane & 15;
  const int l4 = lane >> 4;

  const int hw = blockIdx.x;          // 0..1535
  const int xcd = hw & 7;
  const int r = hw >> 3;
  const int tile = xcd * 64 + r / 3;  // 0..511
  const int nblk = r % 3;
  const int b = tile >> 5;
  const int ib = tile & 31;

  const uint32_t* imgb = img + (size_t)b * CIN * 130 * 68;

  // ---- X gather descriptors (2/thread): unit u -> (kk,y,cs,col16) ----
  // LDS row order: ri = kk*12 + y*2 + cs (y=0..5 tile row, cs=channel&1)
  int xsrc[2];
  bool xok[2];
#pragma unroll
  for (int it = 0; it < 2; ++it) {
    const int u = wid * 102 + lane + it * 64;
    const int ri = u / 17;
    const int col16 = u % 17;
    const int kk = ri / 12;
    const int rem = ri % 12;
    const int y = rem >> 1;
    const int cs = rem & 1;
    const int cl = 2 * kk + cs;
    xsrc[it] = (cl * 130 + 4 * ib + y) * 68 + col16 * 4;
    xok[it] = (it == 0) || (lane < 38);
  }

  // ---- A DMA slots (4/thread): verbatim r8 ----
  int aoff[4];
#pragma unroll
  for (int it = 0; it < 4; ++it) {
    const int slot = tid + it * 256;
    const int n = slot >> 3;
    const int u = slot & 7;
    aoff[it] = (nblk * 128 + n) * 1024 + ((u ^ (n & 7)) << 3);
  }

#define STAGE(bs, ckv)                                                     \
  {                                                                        \
    _Pragma("unroll") for (int it = 0; it < 4; ++it) {                     \
      const short* src = keff + aoff[it] + (ckv) * 64;                     \
      __builtin_amdgcn_global_load_lds(                                    \
          (const __attribute__((address_space(1))) void*)src,              \
          (__attribute__((address_space(3))) void*)                        \
              &alds[(bs) * ABUF_DW + (tid + it * 256) * 4],                \
          16, 0, 0);                                                       \
    }                                                                      \
    _Pragma("unroll") for (int it = 0; it < 2; ++it) {                     \
      if (xok[it]) {                                                       \
        const uint32_t* src = imgb + xsrc[it] + (ckv) * (4 * 130 * 68);    \
        __builtin_amdgcn_global_load_lds(                                  \
            (const __attribute__((address_space(1))) void*)src,            \
            (__attribute__((address_space(3))) void*)                      \
                &xlds[(bs) * XBUF_DW + (wid * 102 + it * 64) * 4],         \
            16, 0, 0);                                                     \
      }                                                                    \
    }                                                                      \
  }

  union ufrag { short8_t s8; uint32_t u[4]; };

  floatx4 acc[4][4];
#pragma unroll
  for (int i2 = 0; i2 < 4; ++i2)
#pragma unroll
    for (int j2 = 0; j2 < 4; ++j2) acc[i2][j2] = (floatx4){0.f, 0.f, 0.f, 0.f};

  float biasr[4];
#pragma unroll
  for (int nf = 0; nf < 4; ++nf) biasr[nf] = bias[nblk * 32 + wn * 16 + nf * 4 + l4];

  // X read base: ri0 = kk*12 + 4*wavem + 4*(l4&1) + (l4>>1); dword = ri0*68 + j
  const int xbase = (4 * wavem + 4 * (l4 & 1) + (l4 >> 1)) * 68 + l15;
  // A read base: row n = wn*64 + nf*16 + l15; slot swizzle ((kk<<2)|l4)^(l15&7)
  const int abase = (wn * 64 + l15) * 32 + ((l4 ^ (l15 & 7)) << 2);

#define COMPUTE(ckv)                                                       \
  {                                                                        \
    const uint32_t* Ap = alds + ((ckv) & 1) * ABUF_DW;                     \
    const uint32_t* Xp = xlds + ((ckv) & 1) * XBUF_DW + xbase;             \
    _Pragma("unroll") for (int kk = 0; kk < 2; ++kk) {                     \
      short8_t af[4];                                                      \
      _Pragma("unroll") for (int nf = 0; nf < 4; ++nf)                     \
        af[nf] = *reinterpret_cast<const short8_t*>(                       \
            Ap + (abase ^ (kk << 4)) + nf * 512);                          \
      const uint32_t* Xk = Xp + kk * 816;                                  \
      ufrag xf[4];                                                         \
      _Pragma("unroll") for (int mf = 0; mf < 4; ++mf) {                   \
        const int o = mf * 16;                                             \
        xf[mf].u[0] = Xk[o];                                               \
        xf[mf].u[1] = Xk[o + 1];                                           \
        xf[mf].u[2] = Xk[o + 136];                                         \
        xf[mf].u[3] = Xk[o + 137];                                         \
      }                                                                    \
      _Pragma("unroll") for (int mf = 0; mf < 4; ++mf)                     \
        _Pragma("unroll") for (int nf = 0; nf < 4; ++nf)                   \
          acc[mf][nf] = __builtin_amdgcn_mfma_f32_16x16x32_bf16(           \
              af[nf], xf[mf].s8, acc[mf][nf], 0, 0, 0);                    \
    }                                                                      \
  }

  // prologue: stage chunk 0
  STAGE(0, 0);

  for (int ck = 0; ck < NCK; ++ck) {
    asm volatile("s_waitcnt vmcnt(0) lgkmcnt(0)" ::: "memory");
    __builtin_amdgcn_s_barrier();
    __builtin_amdgcn_sched_barrier(0);
    if (ck < NCK - 1) STAGE((ck + 1) & 1, ck + 1);  // post-barrier: safe overwrite
    __builtin_amdgcn_sched_barrier(0);
    COMPUTE(ck);
  }

  // epilogue (validated mapping)
  const int i_row = ib * 2 + wavem;
  const int orow0 = 2 * i_row;
#pragma unroll
  for (int nf = 0; nf < 4; ++nf) {
    const int o = nblk * 32 + wn * 16 + nf * 4 + l4;
    const float bv = biasr[nf];
    float* obase = out + ((size_t)(b * COUT + o) * IHW + orow0) * IHW;
#pragma unroll
    for (int mf = 0; mf < 4; ++mf) {
      const int col = 2 * (mf * 16 + l15);
      float2 s0 = make_float2(acc[mf][nf][0] + bv, acc[mf][nf][1] + bv);
      float2 s1 = make_float2(acc[mf][nf][2] + bv, acc[mf][nf][3] + bv);
      *reinterpret_cast<float2*>(obase + col) = s0;
      *reinterpret_cast<float2*>(obase + IHW + col) = s1;
    }
  }
#undef STAGE
#undef COMPUTE
}

// ---------------- fallback (r9 kernel, used when ws too small) ----------------
#define FB_P_DW 168
#define FB_COFF 80
#define FB_XBUF (12 * FB_P_DW)

__global__ __launch_bounds__(256) void conv_fb(const float* __restrict__ x,
                                               const short* __restrict__ keff,
                                               const float* __restrict__ bias,
                                               float* __restrict__ out) {
  __shared__ uint32_t xlds[2 * FB_XBUF];
  __shared__ uint32_t alds[2 * ABUF_DW];

  const int tid = threadIdx.x;
  const int lane = tid & 63;
  const int wid = tid >> 6;
  const int wavem = wid >> 1;
  const int wn = wid & 1;
  const int l15 = lane & 15;
  const int l4 = lane >> 4;

  const int hw = blockIdx.x;
  const int xcd = hw & 7;
  const int r = hw >> 3;
  const int tile = xcd * 64 + r / 3;
  const int nblk = r % 3;
  const int b = tile >> 5;
  const int ib = tile & 31;
  const int gy0 = ib * 4 - 1;

  const float* xb = x + (size_t)b * CIN * IHW * IHW;

  int sl_off[3], sl_dw[3], sl_s[3];
  bool sl_ok[3];
#pragma unroll
  for (int it = 0; it < 3; ++it) {
    const int slot = tid + it * 256;
    const int seg = slot >> 5;
    const int s = slot & 31;
    const int c_sub = seg / 12;
    const int rr = seg % 12;
    const int kk2 = rr / 6;
    const int y = rr % 6;
    const int c_loc = 2 * kk2 + c_sub;
    const int gy = gy0 + y;
    const bool ok = (unsigned)gy < (unsigned)IHW;
    sl_off[it] = (c_loc * IHW + (ok ? gy : 0)) * IHW + 4 * s;
    sl_dw[it] = rr * FB_P_DW + c_sub * FB_COFF;
    sl_s[it] = s;
    sl_ok[it] = ok;
  }

  int aoff[4];
#pragma unroll
  for (int it = 0; it < 4; ++it) {
    const int slot = tid + it * 256;
    const int n = slot >> 3;
    const int u = slot & 7;
    aoff[it] = (nblk * 128 + n) * 1024 + ((u ^ (n & 7)) << 3);
  }

  float4 gv[3];
  float gn[3];
#define FISSUE(ckv)                                                       \
  {                                                                       \
    _Pragma("unroll") for (int it = 0; it < 3; ++it) {                    \
      const float* p = xb + sl_off[it] + (size_t)(ckv) * (4 * IHW * IHW); \
      gv[it] = *reinterpret_cast<const float4*>(p);                       \
      gn[it] = (sl_s[it] < 31) ? p[4] : 0.f;                              \
    }                                                                     \
  }
#define FWRITE(bs)                                                        \
  {                                                                       \
    uint32_t* Bp = xlds + (bs) * FB_XBUF;                                 \
    _Pragma("unroll") for (int it = 0; it < 3; ++it) {                    \
      float4 v = gv[it];                                                  \
      float nx = gn[it];                                                  \
      if (!sl_ok[it]) { v.x = 0.f; v.y = 0.f; v.z = 0.f; v.w = 0.f; nx = 0.f; } \
      const int o = sl_dw[it] + 2 * sl_s[it] + 1;                         \
      Bp[o] = pk(v.y, v.z);                                               \
      Bp[o + 1] = pk(v.w, nx);                                            \
      if (sl_s[it] == 0) Bp[sl_dw[it]] = pk(0.f, v.x);                    \
    }                                                                     \
  }
#define FADMA(bs, ckv)                                                    \
  {                                                                       \
    _Pragma("unroll") for (int it = 0; it < 4; ++it) {                    \
      const short* src = keff + aoff[it] + (ckv) * 64;                    \
      __builtin_amdgcn_global_load_lds(                                   \
          (const __attribute__((address_space(1))) void*)src,             \
          (__attribute__((address_space(3))) void*)                       \
              &alds[(bs) * ABUF_DW + (tid + it * 256) * 4],               \
          16, 0, 0);                                                      \
    }                                                                     \
  }

  union ufragf { short8_t s8; uint32_t u[4]; };
#define FKK(Apt, Xkt, abasev)                                             \
  {                                                                       \
    short8_t af[4];                                                       \
    _Pragma("unroll") for (int nf = 0; nf < 4; ++nf)                      \
      af[nf] = *reinterpret_cast<const short8_t*>((Apt) + (abasev) + nf * 512); \
    ufragf xf[4];                                                         \
    _Pragma("unroll") for (int mf = 0; mf < 4; ++mf) {                    \
      xf[mf].u[0] = (Xkt)[mf * 16];                                       \
      xf[mf].u[1] = (Xkt)[mf * 16 + 1];                                   \
      xf[mf].u[2] = (Xkt)[mf * 16 + FB_P_DW];                             \
      xf[mf].u[3] = (Xkt)[mf * 16 + FB_P_DW + 1];                         \
    }                                                                     \
    _Pragma("unroll") for (int mf = 0; mf < 4; ++mf)                      \
      _Pragma("unroll") for (int nf = 0; nf < 4; ++nf)                    \
        acc[mf][nf] = __builtin_amdgcn_mfma_f32_16x16x32_bf16(            \
            af[nf], xf[mf].s8, acc[mf][nf], 0, 0, 0);                     \
  }

  floatx4 acc[4][4];
#pragma unroll
  for (int i2 = 0; i2 < 4; ++i2)
#pragma unroll
    for (int j2 = 0; j2 < 4; ++j2) acc[i2][j2] = (floatx4){0.f, 0.f, 0.f, 0.f};

  float biasr[4];
#pragma unroll
  for (int nf = 0; nf < 4; ++nf) biasr[nf] = bias[nblk * 32 + wn * 16 + nf * 4 + l4];

  const int cm_dw = (2 * wavem + 2 * (l4 & 1)) * FB_P_DW + (l4 >> 1) * FB_COFF + l15;
  const int a0 = (wn * 64 + l15) * 32 + ((l4 ^ (l15 & 7)) << 2);
  const int a1 = a0 ^ 16;

  FISSUE(0);
  FADMA(0, 0);
  FWRITE(0);
  FISSUE(1);

  for (int ck = 0; ck < NCK - 1; ++ck) {
    asm volatile("s_waitcnt vmcnt(6) lgkmcnt(0)" ::: "memory");
    __builtin_amdgcn_s_barrier();
    __builtin_amdgcn_sched_barrier(0);
    const int cur = ck & 1;
    const uint32_t* Ap = alds + cur * ABUF_DW;
    const uint32_t* Xk0 = xlds + cur * FB_XBUF + cm_dw;
    const uint32_t* Xk1 = Xk0 + 6 * FB_P_DW;
    FADMA(cur ^ 1, ck + 1);
    FKK(Ap, Xk0, a0);
    FKK(Ap, Xk1, a1);
    FWRITE(cur ^ 1);
    if (ck + 2 < NCK) FISSUE(ck + 2);
  }
  asm volatile("s_waitcnt vmcnt(0) lgkmcnt(0)" ::: "memory");
  __builtin_amdgcn_s_barrier();
  __builtin_amdgcn_sched_barrier(0);
  {
    const uint32_t* Ap = alds + ABUF_DW;
    const uint32_t* Xk0 = xlds + FB_XBUF + cm_dw;
    const uint32_t* Xk1 = Xk0 + 6 * FB_P_DW;
    FKK(Ap, Xk0, a0);
    FKK(Ap, Xk1, a1);
  }

  const int i_row = ib * 2 + wavem;
  const int orow0 = 2 * i_row;
#pragma unroll
  for (int nf = 0; nf < 4; ++nf) {
    const int o = nblk * 32 + wn * 16 + nf * 4 + l4;
    const float bv = biasr[nf];
    float* obase = out + ((size_t)(b * COUT + o) * IHW + orow0) * IHW;
#pragma unroll
    for (int mf = 0; mf < 4; ++mf) {
      const int col = 2 * (mf * 16 + l15);
      float2 s0 = make_float2(acc[mf][nf][0] + bv, acc[mf][nf][1] + bv);
      float2 s1 = make_float2(acc[mf][nf][2] + bv, acc[mf][nf][3] + bv);
      *reinterpret_cast<float2*>(obase + col) = s0;
      *reinterpret_cast<float2*>(obase + IHW + col) = s1;
    }
  }
#undef FISSUE
#undef FWRITE
#undef FADMA
#undef FKK
}

extern "C" void kernel_launch(void* const* d_in, const int* in_sizes, int n_in,
                              void* d_out, int out_size, void* d_ws, size_t ws_size,
                              hipStream_t stream) {
  const float* x = (const float*)d_in[0];
  const float* w = (const float*)d_in[1];
  const float* bias = (const float*)d_in[2];
  float* out = (float*)d_out;
  short* keff = (short*)d_ws;                       // 786,432 B
  uint32_t* img = (uint32_t*)((char*)d_ws + 786432);  // 36,208,640 B

  const size_t NEED = 786432 + (size_t)16 * 64 * 130 * 272;  // 36,995,072

  hipLaunchKernelGGL(keff_kernel, dim3(24), dim3(256), 0, stream, w, keff);
  if (ws_size >= NEED) {
    hipLaunchKernelGGL(prepass, dim3(8840), dim3(256), 0, stream, x, img);
    hipLaunchKernelGGL(conv_mfma, dim3(1536), dim3(256), 0, stream, img, keff, bias, out);
  } else {
    hipLaunchKernelGGL(conv_fb, dim3(1536), dim3(256), 0, stream, x, keff, bias, out);
  }
}

// Round 12
// 84.549 us; speedup vs baseline: 1.2420x; 1.2420x over previous
//
#include <hip/hip_runtime.h>
#include <hip/hip_bf16.h>
#include <cstddef>
#include <cstdint>

// Direct-conv reformulation of the Winograd reference (validated r1-r11):
// out[b,o,2i+p,2j+q] = bias[o] + sum_{c,y,x} xpad[b,c,2i-1+y,2j-1+x] * Keff[o,c,p,q,y,x]
// Implicit GEMM: M=65536, N=384, K=1024, bf16 MFMA. Round 12:
//  1) prepass vectorized: 32 lanes/row, aligned float4 loads + shfl_up for the
//     -1 column shift, aligned uint2 stores (was 8 scalar loads/thread, ~40us).
//  2) conv: counted-vmcnt schedule (T4): stage 2 chunks ahead, per-chunk
//     {vmcnt(6); barrier; COMPUTE; barrier; STAGE(ck+2)} -- DMA queue never
//     drains mid-loop (only the peeled last chunk uses vmcnt(0)).
//  COMPUTE, layouts, grid identical to the passing r11 kernel.

#define IHW 128
#define CIN 64
#define COUT 96
#define NCK 16

typedef __attribute__((ext_vector_type(8))) short short8_t;
typedef __attribute__((ext_vector_type(4))) float floatx4;

__device__ __forceinline__ short bf16r(float f) {
  uint32_t u = __float_as_uint(f);
  uint32_t r = (u + 0x7FFFu + ((u >> 16) & 1u)) >> 16;
  return (short)r;
}

__device__ __forceinline__ uint32_t pk(float lo, float hi) {
  union { __hip_bfloat16 h; unsigned short s; } a, bq;
  a.h = __float2bfloat16(lo);
  bq.h = __float2bfloat16(hi);
  return (uint32_t)a.s | ((uint32_t)bq.s << 16);
}

// ---------------- Keff precompute ----------------
__global__ void keff_kernel(const float* __restrict__ w, short* __restrict__ keff) {
  int idx = blockIdx.x * 256 + threadIdx.x;
  if (idx >= COUT * CIN) return;
  int o = idx / CIN, c = idx % CIN;
  int g = o / 32;

  int perm[4] = {0, 1, 2, 3};
  if (g == 1) { perm[0] = 1; perm[1] = 0; }
  else if (g == 2) { perm[0] = 3; perm[3] = 0; }

  const float H[4][4] = {{1,1,1,1},{1,-1,1,-1},{1,1,-1,-1},{1,-1,-1,1}};
  float S[2][4];
#pragma unroll
  for (int p = 0; p < 2; ++p)
#pragma unroll
    for (int a = 0; a < 4; ++a) {
      bool pos = (g == 1) ? ((p == 0) ? true : (a < 2))
                          : ((p == 0) ? ((a & 1) == 0) : (a < 2));
      S[p][a] = pos ? 1.f : -1.f;
    }

  float wv[4][4];
#pragma unroll
  for (int a = 0; a < 4; ++a)
#pragma unroll
    for (int d = 0; d < 4; ++d) wv[a][d] = w[(o * CIN + c) * 16 + a * 4 + d];

  for (int p = 0; p < 2; ++p)
    for (int q = 0; q < 2; ++q) {
      int n = o * 4 + p * 2 + q;
      for (int y = 0; y < 4; ++y)
        for (int xx = 0; xx < 4; ++xx) {
          float s = 0.f;
#pragma unroll
          for (int a = 0; a < 4; ++a) {
            float ea = S[p][a] * H[a][perm[xx]];
#pragma unroll
            for (int d = 0; d < 4; ++d) s += ea * S[q][d] * H[d][perm[y]] * wv[a][d];
          }
          keff[n * 1024 + c * 16 + y * 4 + xx] = bf16r(s);
        }
    }
}

// ---------------- pre-pass: fp32 x -> padded bf16 image (vectorized) ----------------
// I[(b*64+c)*130 + py][68 dw]; pc = gx+1 (pc 0 & 129..135 pad); rows py=0,129 zero.
// 32 lanes per row: lane l loads aligned float4 (gx 4l..4l+3), shfl_up supplies
// gx 4l-1; writes uint2 at dword 2l; lane 31 writes the 16B tail pad unit.
__global__ __launch_bounds__(256) void prepass(const float* __restrict__ x,
                                               uint32_t* __restrict__ img) {
  const int t = blockIdx.x * 256 + threadIdx.x;
  const int r = t >> 5;   // row 0..133119
  const int l = t & 31;
  const int py = r % 130;
  const int rc = r / 130;  // b*64 + c

  uint32_t d0 = 0, d1 = 0, t0 = 0;
  if (py != 0 && py != 129) {
    const float4 v = *reinterpret_cast<const float4*>(
        x + ((size_t)rc * IHW + (py - 1)) * IHW + 4 * l);
    float prev = __shfl_up(v.w, 1, 32);
    if (l == 0) prev = 0.f;
    d0 = pk(prev, v.x);   // pc 4l+0,4l+1 = gx 4l-1,4l
    d1 = pk(v.y, v.z);    // pc 4l+2,4l+3 = gx 4l+1,4l+2
    t0 = pk(v.w, 0.f);    // pc 128,129 = gx 127,pad (lane 31 only)
  }
  uint32_t* row = img + (size_t)r * 68;
  *reinterpret_cast<uint2*>(row + 2 * l) = make_uint2(d0, d1);
  if (l == 31) *reinterpret_cast<uint4*>(row + 64) = make_uint4(t0, 0, 0, 0);
}

// ---------------- main conv kernel ----------------
// block: 256 threads = 4 waves (2 M x 2 N). Tile M=128 (i-pair x 64 j), N=128.
// grid 1536, XCD-paired. LDS: A dbuf 2x16K + X dbuf 2x6528B.
#define XBUF_DW 1632
#define ABUF_DW 4096

__global__ __launch_bounds__(256) void conv_mfma(const uint32_t* __restrict__ img,
                                                 const short* __restrict__ keff,
                                                 const float* __restrict__ bias,
                                                 float* __restrict__ out) {
  __shared__ uint32_t xlds[2 * XBUF_DW];  // 13,056 B
  __shared__ uint32_t alds[2 * ABUF_DW];  // 32,768 B

  const int tid = threadIdx.x;
  const int lane = tid & 63;
  const int wid = tid >> 6;
  const int wavem = wid >> 1;
  const int wn = wid & 1;
  const int l15 = lane & 15;
  const int l4 = lane >> 4;

  const int hw = blockIdx.x;          // 0..1535
  const int xcd = hw & 7;
  const int r = hw >> 3;
  const int tile = xcd * 64 + r / 3;  // 0..511
  const int nblk = r % 3;
  const int b = tile >> 5;
  const int ib = tile & 31;

  const uint32_t* imgb = img + (size_t)b * CIN * 130 * 68;

  // ---- X gather descriptors (2/thread): unit u -> (kk,y,cs,col16) ----
  int xsrc[2];
  bool xok[2];
#pragma unroll
  for (int it = 0; it < 2; ++it) {
    const int u = wid * 102 + lane + it * 64;
    const int ri = u / 17;
    const int col16 = u % 17;
    const int kk = ri / 12;
    const int rem = ri % 12;
    const int y = rem >> 1;
    const int cs = rem & 1;
    const int cl = 2 * kk + cs;
    xsrc[it] = (cl * 130 + 4 * ib + y) * 68 + col16 * 4;
    xok[it] = (it == 0) || (lane < 38);
  }

  // ---- A DMA slots (4/thread): verbatim r8 ----
  int aoff[4];
#pragma unroll
  for (int it = 0; it < 4; ++it) {
    const int slot = tid + it * 256;
    const int n = slot >> 3;
    const int u = slot & 7;
    aoff[it] = (nblk * 128 + n) * 1024 + ((u ^ (n & 7)) << 3);
  }

#define STAGE(bs, ckv)                                                     \
  {                                                                        \
    _Pragma("unroll") for (int it = 0; it < 4; ++it) {                     \
      const short* src = keff + aoff[it] + (ckv) * 64;                     \
      __builtin_amdgcn_global_load_lds(                                    \
          (const __attribute__((address_space(1))) void*)src,              \
          (__attribute__((address_space(3))) void*)                        \
              &alds[(bs) * ABUF_DW + (tid + it * 256) * 4],                \
          16, 0, 0);                                                       \
    }                                                                      \
    _Pragma("unroll") for (int it = 0; it < 2; ++it) {                     \
      if (xok[it]) {                                                       \
        const uint32_t* src = imgb + xsrc[it] + (ckv) * (4 * 130 * 68);    \
        __builtin_amdgcn_global_load_lds(                                  \
            (const __attribute__((address_space(1))) void*)src,            \
            (__attribute__((address_space(3))) void*)                      \
                &xlds[(bs) * XBUF_DW + (wid * 102 + it * 64) * 4],         \
            16, 0, 0);                                                     \
      }                                                                    \
    }                                                                      \
  }

  union ufrag { short8_t s8; uint32_t u[4]; };

  floatx4 acc[4][4];
#pragma unroll
  for (int i2 = 0; i2 < 4; ++i2)
#pragma unroll
    for (int j2 = 0; j2 < 4; ++j2) acc[i2][j2] = (floatx4){0.f, 0.f, 0.f, 0.f};

  float biasr[4];
#pragma unroll
  for (int nf = 0; nf < 4; ++nf) biasr[nf] = bias[nblk * 32 + wn * 16 + nf * 4 + l4];

  const int xbase = (4 * wavem + 4 * (l4 & 1) + (l4 >> 1)) * 68 + l15;
  const int abase = (wn * 64 + l15) * 32 + ((l4 ^ (l15 & 7)) << 2);

#define COMPUTE(ckv)                                                       \
  {                                                                        \
    const uint32_t* Ap = alds + ((ckv) & 1) * ABUF_DW;                     \
    const uint32_t* Xp = xlds + ((ckv) & 1) * XBUF_DW + xbase;             \
    _Pragma("unroll") for (int kk = 0; kk < 2; ++kk) {                     \
      short8_t af[4];                                                      \
      _Pragma("unroll") for (int nf = 0; nf < 4; ++nf)                     \
        af[nf] = *reinterpret_cast<const short8_t*>(                       \
            Ap + (abase ^ (kk << 4)) + nf * 512);                          \
      const uint32_t* Xk = Xp + kk * 816;                                  \
      ufrag xf[4];                                                         \
      _Pragma("unroll") for (int mf = 0; mf < 4; ++mf) {                   \
        const int o = mf * 16;                                             \
        xf[mf].u[0] = Xk[o];                                               \
        xf[mf].u[1] = Xk[o + 1];                                           \
        xf[mf].u[2] = Xk[o + 136];                                         \
        xf[mf].u[3] = Xk[o + 137];                                         \
      }                                                                    \
      _Pragma("unroll") for (int mf = 0; mf < 4; ++mf)                     \
        _Pragma("unroll") for (int nf = 0; nf < 4; ++nf)                   \
          acc[mf][nf] = __builtin_amdgcn_mfma_f32_16x16x32_bf16(           \
              af[nf], xf[mf].s8, acc[mf][nf], 0, 0, 0);                    \
    }                                                                      \
  }

  // prologue: two chunks in flight (12 outstanding DMAs)
  STAGE(0, 0);
  STAGE(1, 1);

  for (int ck = 0; ck < NCK - 1; ++ck) {
    asm volatile("s_waitcnt vmcnt(6) lgkmcnt(0)" ::: "memory");  // ck done; ck+1 in flight
    __builtin_amdgcn_s_barrier();
    __builtin_amdgcn_sched_barrier(0);
    COMPUTE(ck);
    if (ck + 2 < NCK) {
      __builtin_amdgcn_s_barrier();       // all waves done reading buf ck&1
      __builtin_amdgcn_sched_barrier(0);
      STAGE(ck & 1, ck + 2);              // refill; stays in flight across next wait
    }
  }
  // peeled last chunk
  asm volatile("s_waitcnt vmcnt(0) lgkmcnt(0)" ::: "memory");
  __builtin_amdgcn_s_barrier();
  __builtin_amdgcn_sched_barrier(0);
  COMPUTE(NCK - 1);

  // epilogue (validated mapping)
  const int i_row = ib * 2 + wavem;
  const int orow0 = 2 * i_row;
#pragma unroll
  for (int nf = 0; nf < 4; ++nf) {
    const int o = nblk * 32 + wn * 16 + nf * 4 + l4;
    const float bv = biasr[nf];
    float* obase = out + ((size_t)(b * COUT + o) * IHW + orow0) * IHW;
#pragma unroll
    for (int mf = 0; mf < 4; ++mf) {
      const int col = 2 * (mf * 16 + l15);
      float2 s0 = make_float2(acc[mf][nf][0] + bv, acc[mf][nf][1] + bv);
      float2 s1 = make_float2(acc[mf][nf][2] + bv, acc[mf][nf][3] + bv);
      *reinterpret_cast<float2*>(obase + col) = s0;
      *reinterpret_cast<float2*>(obase + IHW + col) = s1;
    }
  }
#undef STAGE
#undef COMPUTE
}

// ---------------- fallback (r9 kernel, used when ws too small) ----------------
#define FB_P_DW 168
#define FB_COFF 80
#define FB_XBUF (12 * FB_P_DW)

__global__ __launch_bounds__(256) void conv_fb(const float* __restrict__ x,
                                               const short* __restrict__ keff,
                                               const float* __restrict__ bias,
                                               float* __restrict__ out) {
  __shared__ uint32_t xlds[2 * FB_XBUF];
  __shared__ uint32_t alds[2 * ABUF_DW];

  const int tid = threadIdx.x;
  const int lane = tid & 63;
  const int wid = tid >> 6;
  const int wavem = wid >> 1;
  const int wn = wid & 1;
  const int l15 = lane & 15;
  const int l4 = lane >> 4;

  const int hw = blockIdx.x;
  const int xcd = hw & 7;
  const int r = hw >> 3;
  const int tile = xcd * 64 + r / 3;
  const int nblk = r % 3;
  const int b = tile >> 5;
  const int ib = tile & 31;
  const int gy0 = ib * 4 - 1;

  const float* xb = x + (size_t)b * CIN * IHW * IHW;

  int sl_off[3], sl_dw[3], sl_s[3];
  bool sl_ok[3];
#pragma unroll
  for (int it = 0; it < 3; ++it) {
    const int slot = tid + it * 256;
    const int seg = slot >> 5;
    const int s = slot & 31;
    const int c_sub = seg / 12;
    const int rr = seg % 12;
    const int kk2 = rr / 6;
    const int y = rr % 6;
    const int c_loc = 2 * kk2 + c_sub;
    const int gy = gy0 + y;
    const bool ok = (unsigned)gy < (unsigned)IHW;
    sl_off[it] = (c_loc * IHW + (ok ? gy : 0)) * IHW + 4 * s;
    sl_dw[it] = rr * FB_P_DW + c_sub * FB_COFF;
    sl_s[it] = s;
    sl_ok[it] = ok;
  }

  int aoff[4];
#pragma unroll
  for (int it = 0; it < 4; ++it) {
    const int slot = tid + it * 256;
    const int n = slot >> 3;
    const int u = slot & 7;
    aoff[it] = (nblk * 128 + n) * 1024 + ((u ^ (n & 7)) << 3);
  }

  float4 gv[3];
  float gn[3];
#define FISSUE(ckv)                                                       \
  {                                                                       \
    _Pragma("unroll") for (int it = 0; it < 3; ++it) {                    \
      const float* p = xb + sl_off[it] + (size_t)(ckv) * (4 * IHW * IHW); \
      gv[it] = *reinterpret_cast<const float4*>(p);                       \
      gn[it] = (sl_s[it] < 31) ? p[4] : 0.f;                              \
    }                                                                     \
  }
#define FWRITE(bs)                                                        \
  {                                                                       \
    uint32_t* Bp = xlds + (bs) * FB_XBUF;                                 \
    _Pragma("unroll") for (int it = 0; it < 3; ++it) {                    \
      float4 v = gv[it];                                                  \
      float nx = gn[it];                                                  \
      if (!sl_ok[it]) { v.x = 0.f; v.y = 0.f; v.z = 0.f; v.w = 0.f; nx = 0.f; } \
      const int o = sl_dw[it] + 2 * sl_s[it] + 1;                         \
      Bp[o] = pk(v.y, v.z);                                               \
      Bp[o + 1] = pk(v.w, nx);                                            \
      if (sl_s[it] == 0) Bp[sl_dw[it]] = pk(0.f, v.x);                    \
    }                                                                     \
  }
#define FADMA(bs, ckv)                                                    \
  {                                                                       \
    _Pragma("unroll") for (int it = 0; it < 4; ++it) {                    \
      const short* src = keff + aoff[it] + (ckv) * 64;                    \
      __builtin_amdgcn_global_load_lds(                                   \
          (const __attribute__((address_space(1))) void*)src,             \
          (__attribute__((address_space(3))) void*)                       \
              &alds[(bs) * ABUF_DW + (tid + it * 256) * 4],               \
          16, 0, 0);                                                      \
    }                                                                     \
  }

  union ufragf { short8_t s8; uint32_t u[4]; };
#define FKK(Apt, Xkt, abasev)                                             \
  {                                                                       \
    short8_t af[4];                                                       \
    _Pragma("unroll") for (int nf = 0; nf < 4; ++nf)                      \
      af[nf] = *reinterpret_cast<const short8_t*>((Apt) + (abasev) + nf * 512); \
    ufragf xf[4];                                                         \
    _Pragma("unroll") for (int mf = 0; mf < 4; ++mf) {                    \
      xf[mf].u[0] = (Xkt)[mf * 16];                                       \
      xf[mf].u[1] = (Xkt)[mf * 16 + 1];                                   \
      xf[mf].u[2] = (Xkt)[mf * 16 + FB_P_DW];                             \
      xf[mf].u[3] = (Xkt)[mf * 16 + FB_P_DW + 1];                         \
    }                                                                     \
    _Pragma("unroll") for (int mf = 0; mf < 4; ++mf)                      \
      _Pragma("unroll") for (int nf = 0; nf < 4; ++nf)                    \
        acc[mf][nf] = __builtin_amdgcn_mfma_f32_16x16x32_bf16(            \
            af[nf], xf[mf].s8, acc[mf][nf], 0, 0, 0);                     \
  }

  floatx4 acc[4][4];
#pragma unroll
  for (int i2 = 0; i2 < 4; ++i2)
#pragma unroll
    for (int j2 = 0; j2 < 4; ++j2) acc[i2][j2] = (floatx4){0.f, 0.f, 0.f, 0.f};

  float biasr[4];
#pragma unroll
  for (int nf = 0; nf < 4; ++nf) biasr[nf] = bias[nblk * 32 + wn * 16 + nf * 4 + l4];

  const int cm_dw = (2 * wavem + 2 * (l4 & 1)) * FB_P_DW + (l4 >> 1) * FB_COFF + l15;
  const int a0 = (wn * 64 + l15) * 32 + ((l4 ^ (l15 & 7)) << 2);
  const int a1 = a0 ^ 16;

  FISSUE(0);
  FADMA(0, 0);
  FWRITE(0);
  FISSUE(1);

  for (int ck = 0; ck < NCK - 1; ++ck) {
    asm volatile("s_waitcnt vmcnt(6) lgkmcnt(0)" ::: "memory");
    __builtin_amdgcn_s_barrier();
    __builtin_amdgcn_sched_barrier(0);
    const int cur = ck & 1;
    const uint32_t* Ap = alds + cur * ABUF_DW;
    const uint32_t* Xk0 = xlds + cur * FB_XBUF + cm_dw;
    const uint32_t* Xk1 = Xk0 + 6 * FB_P_DW;
    FADMA(cur ^ 1, ck + 1);
    FKK(Ap, Xk0, a0);
    FKK(Ap, Xk1, a1);
    FWRITE(cur ^ 1);
    if (ck + 2 < NCK) FISSUE(ck + 2);
  }
  asm volatile("s_waitcnt vmcnt(0) lgkmcnt(0)" ::: "memory");
  __builtin_amdgcn_s_barrier();
  __builtin_amdgcn_sched_barrier(0);
  {
    const uint32_t* Ap = alds + ABUF_DW;
    const uint32_t* Xk0 = xlds + FB_XBUF + cm_dw;
    const uint32_t* Xk1 = Xk0 + 6 * FB_P_DW;
    FKK(Ap, Xk0, a0);
    FKK(Ap, Xk1, a1);
  }

  const int i_row = ib * 2 + wavem;
  const int orow0 = 2 * i_row;
#pragma unroll
  for (int nf = 0; nf < 4; ++nf) {
    const int o = nblk * 32 + wn * 16 + nf * 4 + l4;
    const float bv = biasr[nf];
    float* obase = out + ((size_t)(b * COUT + o) * IHW + orow0) * IHW;
#pragma unroll
    for (int mf = 0; mf < 4; ++mf) {
      const int col = 2 * (mf * 16 + l15);
      float2 s0 = make_float2(acc[mf][nf][0] + bv, acc[mf][nf][1] + bv);
      float2 s1 = make_float2(acc[mf][nf][2] + bv, acc[mf][nf][3] + bv);
      *reinterpret_cast<float2*>(obase + col) = s0;
      *reinterpret_cast<float2*>(obase + IHW + col) = s1;
    }
  }
#undef FISSUE
#undef FWRITE
#undef FADMA
#undef FKK
}

extern "C" void kernel_launch(void* const* d_in, const int* in_sizes, int n_in,
                              void* d_out, int out_size, void* d_ws, size_t ws_size,
                              hipStream_t stream) {
  const float* x = (const float*)d_in[0];
  const float* w = (const float*)d_in[1];
  const float* bias = (const float*)d_in[2];
  float* out = (float*)d_out;
  short* keff = (short*)d_ws;                         // 786,432 B
  uint32_t* img = (uint32_t*)((char*)d_ws + 786432);  // 36,208,640 B

  const size_t NEED = 786432 + (size_t)16 * 64 * 130 * 272;  // 36,995,072

  hipLaunchKernelGGL(keff_kernel, dim3(24), dim3(256), 0, stream, w, keff);
  if (ws_size >= NEED) {
    hipLaunchKernelGGL(prepass, dim3(16640), dim3(256), 0, stream, x, img);
    hipLaunchKernelGGL(conv_mfma, dim3(1536), dim3(256), 0, stream, img, keff, bias, out);
  } else {
    hipLaunchKernelGGL(conv_fb, dim3(1536), dim3(256), 0, stream, x, keff, bias, out);
  }
}